// Round 1
// baseline (1116.814 us; speedup 1.0000x reference)
//
#include <hip/hip_runtime.h>
#include <math.h>

#define NB 8
#define NS 1024
#define NF 512
#define NE 64
#define NH 16

// ---------------- Projection GEMM: C = A(8192 x 512) @ W(512 x N) + bias ----------
// MODE 0: N=2048 KV proj; n -> (e = n>>5, h = (n>>1)&15, c = n&1) -> K/V[b][h][s][e]
// MODE 1: N=1024 Q  proj; n -> (e = n>>4, h = n&15)               -> Q[b][h][s][e]
// Bs is stored PERMUTED so the compute loop reads contiguous [tx*8 .. tx*8+7] and the
// epilogue writes float4-contiguous-in-e chunks (h == tx for the whole micro-tile).
template <int MODE>
__global__ __launch_bounds__(256) void proj_kernel(
    const float* __restrict__ A, const float* __restrict__ W,
    const float* __restrict__ bias, float* __restrict__ out0,
    float* __restrict__ out1, int N)
{
  __shared__ float As[16][132];  // [k][m] transposed
  __shared__ float Bs[16][132];  // [k][sigma(n)] permuted
  const int t = threadIdx.x;
  const int tx = t & 15, ty = t >> 4;
  const int m0 = blockIdx.y * 128;
  const int n0 = blockIdx.x * 128;

  float acc[8][8];
  #pragma unroll
  for (int i = 0; i < 8; ++i)
    #pragma unroll
    for (int j = 0; j < 8; ++j) acc[i][j] = 0.f;

  for (int k0 = 0; k0 < NF; k0 += 16) {
    #pragma unroll
    for (int p = 0; p < 2; ++p) {
      int idx = p * 256 + t;
      int row = idx >> 2, kk = (idx & 3) * 4;
      float4 av = *(const float4*)(A + (size_t)(m0 + row) * NF + k0 + kk);
      As[kk + 0][row] = av.x; As[kk + 1][row] = av.y;
      As[kk + 2][row] = av.z; As[kk + 3][row] = av.w;
      int krow = idx >> 5, c4 = (idx & 31) * 4;
      float4 bv = *(const float4*)(W + (size_t)(k0 + krow) * N + n0 + c4);
      float bw[4] = {bv.x, bv.y, bv.z, bv.w};
      #pragma unroll
      for (int q = 0; q < 4; ++q) {
        int n = c4 + q;
        int col = (MODE == 0) ? (((n >> 1) & 15) * 8 + (n >> 5) * 2 + (n & 1))
                              : ((n & 15) * 8 + (n >> 4));
        Bs[krow][col] = bw[q];
      }
    }
    __syncthreads();
    #pragma unroll
    for (int kk = 0; kk < 16; ++kk) {
      float a[8], b[8];
      *(float4*)&a[0] = *(const float4*)&As[kk][ty * 8];
      *(float4*)&a[4] = *(const float4*)&As[kk][ty * 8 + 4];
      *(float4*)&b[0] = *(const float4*)&Bs[kk][tx * 8];
      *(float4*)&b[4] = *(const float4*)&Bs[kk][tx * 8 + 4];
      #pragma unroll
      for (int i = 0; i < 8; ++i)
        #pragma unroll
        for (int j = 0; j < 8; ++j) acc[i][j] += a[i] * b[j];
    }
    __syncthreads();
  }

  #pragma unroll
  for (int i = 0; i < 8; ++i) {
    int m = m0 + ty * 8 + i;
    int bb = m >> 10, s = m & 1023;
    if (MODE == 0) {
      // thread tx owns head h = tx; j = el*2 + c; 4 consecutive e per float4
      int e0 = n0 >> 5;
      float4 kv, vv;
      float* ka = &kv.x; float* va = &vv.x;
      #pragma unroll
      for (int el = 0; el < 4; ++el) {
        int nK = n0 + el * 32 + tx * 2;
        ka[el] = acc[i][el * 2 + 0] + bias[nK];
        va[el] = acc[i][el * 2 + 1] + bias[nK + 1];
      }
      size_t base = (((size_t)bb * NH + tx) * NS + s) * NE + e0;
      *(float4*)(out0 + base) = kv;
      *(float4*)(out1 + base) = vv;
    } else {
      // thread tx owns head h = tx; j = el; 8 consecutive e
      int e0 = n0 >> 4;
      float4 q0, q1;
      float* qa = &q0.x; float* qb = &q1.x;
      #pragma unroll
      for (int el = 0; el < 4; ++el) {
        qa[el] = acc[i][el]     + bias[n0 + el * 16 + tx];
        qb[el] = acc[i][el + 4] + bias[n0 + (el + 4) * 16 + tx];
      }
      size_t base = (((size_t)bb * NH + tx) * NS + s) * NE + e0;
      *(float4*)(out0 + base)     = q0;
      *(float4*)(out0 + base + 4) = q1;
    }
  }
}

// ---------------- Flash attention, fp32, 64-row Q tiles --------------------------
// grid (S/64, H, B), 256 threads. Thread (tx,ty): rows ty*4+i, QK keys tx+16j,
// PV e-cols tx*4+j. Row stats shuffle-reduced over the 16 contiguous lanes (same ty).
__global__ __launch_bounds__(256) void attn_kernel(
    const float* __restrict__ Q, const float* __restrict__ K,
    const float* __restrict__ V, float* __restrict__ out)
{
  __shared__ float Qs[64][68];
  __shared__ float Ks[64][68];
  __shared__ float Vs[64][68];
  __shared__ float Ps[64][68];
  const int t = threadIdx.x;
  const int tx = t & 15, ty = t >> 4;
  const int qt = blockIdx.x, h = blockIdx.y, b = blockIdx.z;

  const size_t bh = (((size_t)b * NH + h) * NS) * NE;

  #pragma unroll
  for (int p = 0; p < 4; ++p) {
    int idx = p * 256 + t;
    int row = idx >> 4, e4 = (idx & 15) * 4;
    *(float4*)&Qs[row][e4] =
        *(const float4*)(Q + bh + (size_t)(qt * 64 + row) * NE + e4);
  }

  float m[4], l[4], O[4][4];
  #pragma unroll
  for (int i = 0; i < 4; ++i) {
    m[i] = -INFINITY; l[i] = 0.f;
    #pragma unroll
    for (int j = 0; j < 4; ++j) O[i][j] = 0.f;
  }

  for (int kt = 0; kt < NS / 64; ++kt) {
    #pragma unroll
    for (int p = 0; p < 4; ++p) {
      int idx = p * 256 + t;
      int row = idx >> 4, e4 = (idx & 15) * 4;
      size_t g = bh + (size_t)(kt * 64 + row) * NE + e4;
      *(float4*)&Ks[row][e4] = *(const float4*)(K + g);
      *(float4*)&Vs[row][e4] = *(const float4*)(V + g);
    }
    __syncthreads();

    // ---- scores: rows ty*4+i  x  keys tx+16j, full dot over E=64
    float sc[4][4];
    #pragma unroll
    for (int i = 0; i < 4; ++i)
      #pragma unroll
      for (int j = 0; j < 4; ++j) sc[i][j] = 0.f;
    #pragma unroll
    for (int e4 = 0; e4 < 64; e4 += 4) {
      float4 q4[4], k4[4];
      #pragma unroll
      for (int i = 0; i < 4; ++i) q4[i] = *(const float4*)&Qs[ty * 4 + i][e4];
      #pragma unroll
      for (int j = 0; j < 4; ++j) k4[j] = *(const float4*)&Ks[tx + 16 * j][e4];
      #pragma unroll
      for (int i = 0; i < 4; ++i)
        #pragma unroll
        for (int j = 0; j < 4; ++j)
          sc[i][j] += q4[i].x * k4[j].x + q4[i].y * k4[j].y +
                      q4[i].z * k4[j].z + q4[i].w * k4[j].w;
    }

    // ---- online softmax per row (reduce across the 16 lanes sharing ty)
    #pragma unroll
    for (int i = 0; i < 4; ++i) {
      float tm = fmaxf(fmaxf(sc[i][0], sc[i][1]), fmaxf(sc[i][2], sc[i][3]));
      #pragma unroll
      for (int d = 1; d < 16; d <<= 1) tm = fmaxf(tm, __shfl_xor(tm, d, 64));
      float mnew = fmaxf(m[i], tm);
      float alpha = __expf(m[i] - mnew);
      m[i] = mnew;
      float ps = 0.f;
      #pragma unroll
      for (int j = 0; j < 4; ++j) {
        float p = __expf(sc[i][j] - mnew);
        sc[i][j] = p; ps += p;
      }
      #pragma unroll
      for (int d = 1; d < 16; d <<= 1) ps += __shfl_xor(ps, d, 64);
      l[i] = l[i] * alpha + ps;
      #pragma unroll
      for (int j = 0; j < 4; ++j) O[i][j] *= alpha;
      #pragma unroll
      for (int j = 0; j < 4; ++j) Ps[ty * 4 + i][tx + 16 * j] = sc[i][j];
    }
    __syncthreads();

    // ---- PV: O[rows ty*4+i][e-cols tx*4+j] += P @ V
    #pragma unroll
    for (int k4 = 0; k4 < 64; k4 += 4) {
      float pr[4][4];
      #pragma unroll
      for (int i = 0; i < 4; ++i) {
        float4 p4 = *(const float4*)&Ps[ty * 4 + i][k4];
        pr[i][0] = p4.x; pr[i][1] = p4.y; pr[i][2] = p4.z; pr[i][3] = p4.w;
      }
      #pragma unroll
      for (int kk = 0; kk < 4; ++kk) {
        float4 v4 = *(const float4*)&Vs[k4 + kk][tx * 4];
        #pragma unroll
        for (int i = 0; i < 4; ++i) {
          O[i][0] += pr[i][kk] * v4.x;
          O[i][1] += pr[i][kk] * v4.y;
          O[i][2] += pr[i][kk] * v4.z;
          O[i][3] += pr[i][kk] * v4.w;
        }
      }
    }
    __syncthreads();
  }

  const float scaling = 0.125f;  // softmax THEN * 1/sqrt(E)
  #pragma unroll
  for (int i = 0; i < 4; ++i) {
    float inv = scaling / l[i];
    float4 o;
    o.x = O[i][0] * inv; o.y = O[i][1] * inv;
    o.z = O[i][2] * inv; o.w = O[i][3] * inv;
    int s = qt * 64 + ty * 4 + i;
    *(float4*)(out + ((size_t)b * NS + s) * (NE * NH) + h * NE + tx * 4) = o;
  }
}

extern "C" void kernel_launch(void* const* d_in, const int* in_sizes, int n_in,
                              void* d_out, int out_size, void* d_ws, size_t ws_size,
                              hipStream_t stream) {
  const float* inputs1 = (const float*)d_in[0];
  const float* inputs2 = (const float*)d_in[1];
  const float* W_kv    = (const float*)d_in[2];
  const float* b_kv    = (const float*)d_in[3];
  const float* W_q     = (const float*)d_in[4];
  const float* b_q     = (const float*)d_in[5];
  float* out = (float*)d_out;
  float* ws  = (float*)d_ws;

  const size_t plane = (size_t)NB * NH * NS * NE;  // 8,388,608 floats
  float* Qb = ws;
  float* Kb = ws + plane;
  float* Vb = ws + 2 * plane;

  dim3 blk(256);
  proj_kernel<0><<<dim3(2048 / 128, 8192 / 128), blk, 0, stream>>>(
      inputs1, W_kv, b_kv, Kb, Vb, 2048);
  proj_kernel<1><<<dim3(1024 / 128, 8192 / 128), blk, 0, stream>>>(
      inputs2, W_q, b_q, Qb, nullptr, 1024);
  attn_kernel<<<dim3(NS / 64, NH, NB), blk, 0, stream>>>(Qb, Kb, Vb, out);
}

// Round 2
// 556.496 us; speedup vs baseline: 2.0069x; 2.0069x over previous
//
#include <hip/hip_runtime.h>
#include <math.h>

#define NB 8
#define NS 1024
#define NF 512
#define NE 64
#define NH 16

typedef __attribute__((ext_vector_type(8))) short short8;
typedef __attribute__((ext_vector_type(4))) float floatx4;

__device__ inline unsigned short f2bf(float f) {
  union { float f; unsigned int u; } c; c.f = f;
  unsigned int u = c.u;
  u += 0x7FFFu + ((u >> 16) & 1u);  // RNE
  return (unsigned short)(u >> 16);
}

// ---------------- Projection GEMM (fp32 compute, bf16 output) --------------------
// MODE 0: N=2048 KV proj -> K/V[b][h][s][e] bf16
// MODE 1: N=1024 Q  proj -> Q[b][h][s][e] bf16
template <int MODE>
__global__ __launch_bounds__(256) void proj_kernel(
    const float* __restrict__ A, const float* __restrict__ W,
    const float* __restrict__ bias, unsigned short* __restrict__ out0,
    unsigned short* __restrict__ out1, int N)
{
  __shared__ float As[16][132];
  __shared__ float Bs[16][132];
  const int t = threadIdx.x;
  const int tx = t & 15, ty = t >> 4;
  const int m0 = blockIdx.y * 128;
  const int n0 = blockIdx.x * 128;

  float acc[8][8];
  #pragma unroll
  for (int i = 0; i < 8; ++i)
    #pragma unroll
    for (int j = 0; j < 8; ++j) acc[i][j] = 0.f;

  for (int k0 = 0; k0 < NF; k0 += 16) {
    #pragma unroll
    for (int p = 0; p < 2; ++p) {
      int idx = p * 256 + t;
      int row = idx >> 2, kk = (idx & 3) * 4;
      float4 av = *(const float4*)(A + (size_t)(m0 + row) * NF + k0 + kk);
      As[kk + 0][row] = av.x; As[kk + 1][row] = av.y;
      As[kk + 2][row] = av.z; As[kk + 3][row] = av.w;
      int krow = idx >> 5, c4 = (idx & 31) * 4;
      float4 bv = *(const float4*)(W + (size_t)(k0 + krow) * N + n0 + c4);
      float bw[4] = {bv.x, bv.y, bv.z, bv.w};
      #pragma unroll
      for (int q = 0; q < 4; ++q) {
        int n = c4 + q;
        int col = (MODE == 0) ? (((n >> 1) & 15) * 8 + (n >> 5) * 2 + (n & 1))
                              : ((n & 15) * 8 + (n >> 4));
        Bs[krow][col] = bw[q];
      }
    }
    __syncthreads();
    #pragma unroll
    for (int kk = 0; kk < 16; ++kk) {
      float a[8], b[8];
      *(float4*)&a[0] = *(const float4*)&As[kk][ty * 8];
      *(float4*)&a[4] = *(const float4*)&As[kk][ty * 8 + 4];
      *(float4*)&b[0] = *(const float4*)&Bs[kk][tx * 8];
      *(float4*)&b[4] = *(const float4*)&Bs[kk][tx * 8 + 4];
      #pragma unroll
      for (int i = 0; i < 8; ++i)
        #pragma unroll
        for (int j = 0; j < 8; ++j) acc[i][j] += a[i] * b[j];
    }
    __syncthreads();
  }

  #pragma unroll
  for (int i = 0; i < 8; ++i) {
    int m = m0 + ty * 8 + i;
    int bb = m >> 10, s = m & 1023;
    if (MODE == 0) {
      int e0 = n0 >> 5;
      ushort4 kv, vv;
      unsigned short* ka = &kv.x; unsigned short* va = &vv.x;
      #pragma unroll
      for (int el = 0; el < 4; ++el) {
        int nK = n0 + el * 32 + tx * 2;
        ka[el] = f2bf(acc[i][el * 2 + 0] + bias[nK]);
        va[el] = f2bf(acc[i][el * 2 + 1] + bias[nK + 1]);
      }
      size_t base = (((size_t)bb * NH + tx) * NS + s) * NE + e0;
      *(ushort4*)(out0 + base) = kv;
      *(ushort4*)(out1 + base) = vv;
    } else {
      int e0 = n0 >> 4;
      ushort4 q0, q1;
      unsigned short* qa = &q0.x; unsigned short* qb = &q1.x;
      #pragma unroll
      for (int el = 0; el < 4; ++el) {
        qa[el] = f2bf(acc[i][el]     + bias[n0 + el * 16 + tx]);
        qb[el] = f2bf(acc[i][el + 4] + bias[n0 + (el + 4) * 16 + tx]);
      }
      size_t base = (((size_t)bb * NH + tx) * NS + s) * NE + e0;
      *(ushort4*)(out0 + base)     = q0;
      *(ushort4*)(out0 + base + 4) = q1;
    }
  }
}

// ---------------- Flash attention, bf16 MFMA 16x16x32 ----------------------------
// grid (S/64, H, B), 256 threads = 4 waves; wave w owns Q rows w*16..w*16+15.
// Score/O rows live in C-layout (row = quad*4+reg) -> alpha/l are register-local.
__global__ __launch_bounds__(256) void attn_kernel(
    const unsigned short* __restrict__ Q, const unsigned short* __restrict__ K,
    const unsigned short* __restrict__ V, float* __restrict__ out)
{
  __shared__ unsigned short Ks[2][64][72];   // [buf][key][e]   pitch 144B
  __shared__ unsigned short Vst[2][64][72];  // [buf][e][key]   transposed
  __shared__ unsigned short Ps[64][72];      // [q][key] per-wave 16-row slabs

  const int t = threadIdx.x;
  const int w = t >> 6;
  const int lane = t & 63;
  const int quad = lane >> 4;
  const int l16 = lane & 15;
  const int qt = blockIdx.x, h = blockIdx.y, b = blockIdx.z;
  const size_t bh = ((size_t)b * NH + h) * NS * NE;

  // Q A-frags straight from global (A[m=lane&15][k=quad*8+j]), kept in regs
  const unsigned short* qrow = Q + bh + (size_t)(qt * 64 + w * 16 + l16) * NE;
  short8 aq0 = *(const short8*)(qrow + quad * 8);
  short8 aq1 = *(const short8*)(qrow + 32 + quad * 8);

  const int skey = t >> 2, sc4 = t & 3;        // K staging: 32B per thread
  const int vrp  = t >> 3, ve0 = (t & 7) * 8;  // V staging: 2 keys x 8 e

  const unsigned short* Kg = K + bh;
  const unsigned short* Vg = V + bh;

  // ---- stage tile 0 into buf 0
  {
    const unsigned short* kr = Kg + skey * NE + sc4 * 16;
    *(uint4*)&Ks[0][skey][sc4 * 16]     = *(const uint4*)kr;
    *(uint4*)&Ks[0][skey][sc4 * 16 + 8] = *(const uint4*)(kr + 8);
    const unsigned short* vr = Vg + (2 * vrp) * NE + ve0;
    uint4 va = *(const uint4*)vr;
    uint4 vb = *(const uint4*)(vr + NE);
    const unsigned short* pa = (const unsigned short*)&va;
    const unsigned short* pb = (const unsigned short*)&vb;
    #pragma unroll
    for (int j = 0; j < 8; ++j) {
      unsigned int wv = (unsigned int)pa[j] | ((unsigned int)pb[j] << 16);
      *(unsigned int*)&Vst[0][ve0 + j][2 * vrp] = wv;
    }
  }

  float mrow[4], lrow[4];
  floatx4 O[4];
  #pragma unroll
  for (int r = 0; r < 4; ++r) {
    mrow[r] = -INFINITY; lrow[r] = 0.f;
    O[r] = (floatx4){0.f, 0.f, 0.f, 0.f};
  }

  for (int kt = 0; kt < NS / 64; ++kt) {
    __syncthreads();  // bar1: buf[kt&1] staged & visible
    const int bi = kt & 1;

    // prefetch next tile global->regs (hidden under QK+softmax)
    uint4 k0n, k1n, van, vbn;
    if (kt < 15) {
      const unsigned short* kr = Kg + (size_t)(kt + 1) * 64 * NE + skey * NE + sc4 * 16;
      k0n = *(const uint4*)kr;
      k1n = *(const uint4*)(kr + 8);
      const unsigned short* vr = Vg + (size_t)(kt + 1) * 64 * NE + (2 * vrp) * NE + ve0;
      van = *(const uint4*)vr;
      vbn = *(const uint4*)(vr + NE);
    }

    // ---- QK^T: D[q][key], A=Q, B[e][key]=K[key][e]
    floatx4 sc[4];
    #pragma unroll
    for (int kb = 0; kb < 4; ++kb) {
      short8 b0 = *(const short8*)&Ks[bi][kb * 16 + l16][quad * 8];
      short8 b1 = *(const short8*)&Ks[bi][kb * 16 + l16][32 + quad * 8];
      floatx4 z = (floatx4){0.f, 0.f, 0.f, 0.f};
      z = __builtin_amdgcn_mfma_f32_16x16x32_bf16(aq0, b0, z, 0, 0, 0);
      sc[kb] = __builtin_amdgcn_mfma_f32_16x16x32_bf16(aq1, b1, z, 0, 0, 0);
    }

    // ---- online softmax; row = quad*4+r, 16 lanes per row-group
    #pragma unroll
    for (int r = 0; r < 4; ++r) {
      float tm = fmaxf(fmaxf(sc[0][r], sc[1][r]), fmaxf(sc[2][r], sc[3][r]));
      tm = fmaxf(tm, __shfl_xor(tm, 1));
      tm = fmaxf(tm, __shfl_xor(tm, 2));
      tm = fmaxf(tm, __shfl_xor(tm, 4));
      tm = fmaxf(tm, __shfl_xor(tm, 8));
      float mnew = fmaxf(mrow[r], tm);
      float alpha = __expf(mrow[r] - mnew);
      mrow[r] = mnew;
      float p0 = __expf(sc[0][r] - mnew), p1 = __expf(sc[1][r] - mnew);
      float p2 = __expf(sc[2][r] - mnew), p3 = __expf(sc[3][r] - mnew);
      float ps = p0 + p1 + p2 + p3;
      ps += __shfl_xor(ps, 1);
      ps += __shfl_xor(ps, 2);
      ps += __shfl_xor(ps, 4);
      ps += __shfl_xor(ps, 8);
      lrow[r] = lrow[r] * alpha + ps;
      O[0][r] *= alpha; O[1][r] *= alpha; O[2][r] *= alpha; O[3][r] *= alpha;
      const int prow = w * 16 + quad * 4 + r;
      Ps[prow][l16]      = f2bf(p0);
      Ps[prow][16 + l16] = f2bf(p1);
      Ps[prow][32 + l16] = f2bf(p2);
      Ps[prow][48 + l16] = f2bf(p3);
    }

    // ---- stage next tile regs->LDS (other buffer)
    if (kt < 15) {
      const int bn = bi ^ 1;
      *(uint4*)&Ks[bn][skey][sc4 * 16]     = k0n;
      *(uint4*)&Ks[bn][skey][sc4 * 16 + 8] = k1n;
      const unsigned short* pa = (const unsigned short*)&van;
      const unsigned short* pb = (const unsigned short*)&vbn;
      #pragma unroll
      for (int j = 0; j < 8; ++j) {
        unsigned int wv = (unsigned int)pa[j] | ((unsigned int)pb[j] << 16);
        *(unsigned int*)&Vst[bn][ve0 + j][2 * vrp] = wv;
      }
    }
    __syncthreads();  // bar2: Ps visible for PV

    // ---- PV: D[q][e] += P[q][key] V[key][e]; A=P, B[key][e] from Vst[e][key]
    short8 pa0 = *(const short8*)&Ps[w * 16 + l16][quad * 8];
    short8 pa1 = *(const short8*)&Ps[w * 16 + l16][32 + quad * 8];
    #pragma unroll
    for (int eb = 0; eb < 4; ++eb) {
      short8 v0 = *(const short8*)&Vst[bi][eb * 16 + l16][quad * 8];
      short8 v1 = *(const short8*)&Vst[bi][eb * 16 + l16][32 + quad * 8];
      O[eb] = __builtin_amdgcn_mfma_f32_16x16x32_bf16(pa0, v0, O[eb], 0, 0, 0);
      O[eb] = __builtin_amdgcn_mfma_f32_16x16x32_bf16(pa1, v1, O[eb], 0, 0, 0);
    }
  }

  // ---- epilogue: softmax then *1/sqrt(E)
  const float scaling = 0.125f;
  #pragma unroll
  for (int r = 0; r < 4; ++r) {
    float inv = scaling / lrow[r];
    int s = qt * 64 + w * 16 + quad * 4 + r;
    float* orow = out + ((size_t)b * NS + s) * (NE * NH) + h * NE;
    orow[l16]      = O[0][r] * inv;
    orow[16 + l16] = O[1][r] * inv;
    orow[32 + l16] = O[2][r] * inv;
    orow[48 + l16] = O[3][r] * inv;
  }
}

extern "C" void kernel_launch(void* const* d_in, const int* in_sizes, int n_in,
                              void* d_out, int out_size, void* d_ws, size_t ws_size,
                              hipStream_t stream) {
  const float* inputs1 = (const float*)d_in[0];
  const float* inputs2 = (const float*)d_in[1];
  const float* W_kv    = (const float*)d_in[2];
  const float* b_kv    = (const float*)d_in[3];
  const float* W_q     = (const float*)d_in[4];
  const float* b_q     = (const float*)d_in[5];
  float* out = (float*)d_out;

  const size_t plane = (size_t)NB * NH * NS * NE;  // 8,388,608 elements
  unsigned short* Qb = (unsigned short*)d_ws;
  unsigned short* Kb = Qb + plane;
  unsigned short* Vb = Kb + plane;

  dim3 blk(256);
  proj_kernel<0><<<dim3(2048 / 128, 8192 / 128), blk, 0, stream>>>(
      inputs1, W_kv, b_kv, Kb, Vb, 2048);
  proj_kernel<1><<<dim3(1024 / 128, 8192 / 128), blk, 0, stream>>>(
      inputs2, W_q, b_q, Qb, nullptr, 1024);
  attn_kernel<<<dim3(NS / 64, NH, NB), blk, 0, stream>>>(Qb, Kb, Vb, out);
}

// Round 3
// 282.162 us; speedup vs baseline: 3.9581x; 1.9723x over previous
//
#include <hip/hip_runtime.h>
#include <math.h>

#define NB 8
#define NS 1024
#define NF 512
#define NE 64
#define NH 16

typedef __attribute__((ext_vector_type(8))) short short8;
typedef __attribute__((ext_vector_type(4))) float floatx4;

__device__ inline unsigned short f2bf(float f) {
  union { float f; unsigned int u; } c; c.f = f;
  unsigned int u = c.u;
  u += 0x7FFFu + ((u >> 16) & 1u);  // RNE
  return (unsigned short)(u >> 16);
}

__device__ inline void gl_lds16(const void* g, void* l) {
  __builtin_amdgcn_global_load_lds(
      (const __attribute__((address_space(1))) unsigned int*)g,
      (__attribute__((address_space(3))) unsigned int*)l, 16, 0, 0);
}

// ---------------- fp32 -> bf16 convert (row-major) -------------------------------
__global__ __launch_bounds__(256) void conv_bf16(
    const float* __restrict__ in, unsigned short* __restrict__ out, int n4)
{
  int i = blockIdx.x * 256 + threadIdx.x;
  if (i < n4) {
    float4 v = ((const float4*)in)[i];
    ushort4 o;
    o.x = f2bf(v.x); o.y = f2bf(v.y); o.z = f2bf(v.z); o.w = f2bf(v.w);
    ((ushort4*)out)[i] = o;
  }
}

// ---------------- W[k][n] fp32 -> Wt[n'][k] bf16, n' = (n&(G-1))*64 + n>>LOGG ----
// LOGG=5 (KV: n = e*32 + h*2+c -> n' = (h*2+c)*64 + e)
// LOGG=4 (Q:  n = e*16 + h     -> n' = h*64 + e)
template <int LOGG>
__global__ __launch_bounds__(256) void perm_w(
    const float* __restrict__ W, unsigned short* __restrict__ Wt, int N)
{
  __shared__ float T[64][65];
  const int t = threadIdx.x;
  const int k0 = blockIdx.y * 64, n0 = blockIdx.x * 64;
  #pragma unroll
  for (int p = 0; p < 4; ++p) {
    int i = (t >> 4) + p * 16, j = (t & 15) * 4;
    float4 v = *(const float4*)(W + (size_t)(k0 + i) * N + n0 + j);
    T[i][j] = v.x; T[i][j + 1] = v.y; T[i][j + 2] = v.z; T[i][j + 3] = v.w;
  }
  __syncthreads();
  #pragma unroll
  for (int p = 0; p < 2; ++p) {
    int c = p * 256 + t;
    int jn = c >> 3, kc = (c & 7) * 8;
    int n = n0 + jn;
    int g = n & ((1 << LOGG) - 1), e = n >> LOGG;
    unsigned short v[8];
    #pragma unroll
    for (int j = 0; j < 8; ++j) v[j] = f2bf(T[kc + j][jn]);
    *(uint4*)(Wt + (size_t)(g * 64 + e) * NF + k0 + kc) = *(uint4*)v;
  }
}

// ---------------- bf16 MFMA projection GEMM (m97 structure) ----------------------
// C = A(8192x512) @ Wt^T + bias, scattered to bf16 planes [b][h][s][e].
// MODE 0: N=2048, cols (h,c,e); out0=K plane, out1=V plane.
// MODE 1: N=1024, cols (h,e);   out0=Q plane.
template <int MODE>
__global__ __launch_bounds__(256) void gemm_proj(
    const unsigned short* __restrict__ A, const unsigned short* __restrict__ Wt,
    const float* __restrict__ bias, unsigned short* __restrict__ out0,
    unsigned short* __restrict__ out1)
{
  __shared__ union {
    struct { unsigned short A[128 * 32]; unsigned short B[128 * 32]; } ab;
    unsigned short C[128 * 136];  // pitch 136 ushort = 272 B = 17*16 ✓
  } u;

  const int t = threadIdx.x;
  const int w = t >> 6, l = t & 63;
  const int quad = l >> 4, l16 = l & 15;
  const int n0 = blockIdx.x * 128, m0 = blockIdx.y * 128;
  const int wm = (w >> 1) * 64, wn = (w & 1) * 64;

  floatx4 acc[4][4];
  #pragma unroll
  for (int mi = 0; mi < 4; ++mi)
    #pragma unroll
    for (int nj = 0; nj < 4; ++nj) acc[mi][nj] = (floatx4){0.f, 0.f, 0.f, 0.f};

  const int srow = l >> 2, sk = (l & 3) * 8;  // staging: 16 rows/wave/instr
  const unsigned short* Ag = A + (size_t)(m0 + w * 16 + srow) * NF + sk;
  const unsigned short* Bg = Wt + (size_t)(n0 + w * 16 + srow) * NF + sk;

  for (int k0 = 0; k0 < NF; k0 += 32) {
    __syncthreads();  // previous iter's frag reads done before overwrite
    gl_lds16(Ag + k0,            &u.ab.A[(w * 16) * 32]);
    gl_lds16(Ag + 64 * NF + k0,  &u.ab.A[(64 + w * 16) * 32]);
    gl_lds16(Bg + k0,            &u.ab.B[(w * 16) * 32]);
    gl_lds16(Bg + 64 * NF + k0,  &u.ab.B[(64 + w * 16) * 32]);
    __syncthreads();  // staged data visible

    short8 af[4], bf[4];
    #pragma unroll
    for (int mi = 0; mi < 4; ++mi)
      af[mi] = *(const short8*)&u.ab.A[(wm + mi * 16 + l16) * 32 + quad * 8];
    #pragma unroll
    for (int nj = 0; nj < 4; ++nj)
      bf[nj] = *(const short8*)&u.ab.B[(wn + nj * 16 + l16) * 32 + quad * 8];
    #pragma unroll
    for (int mi = 0; mi < 4; ++mi)
      #pragma unroll
      for (int nj = 0; nj < 4; ++nj)
        acc[mi][nj] = __builtin_amdgcn_mfma_f32_16x16x32_bf16(
            af[mi], bf[nj], acc[mi][nj], 0, 0, 0);
  }

  // ---- bias add (col = wave-uniform per (nj,l16)) + stage C to LDS as bf16
  float bv[4];
  #pragma unroll
  for (int nj = 0; nj < 4; ++nj) {
    int np = n0 + wn + nj * 16 + l16;
    int n = (MODE == 0) ? ((np & 63) * 32 + (np >> 6)) : ((np & 63) * 16 + (np >> 6));
    bv[nj] = bias[n];
  }
  __syncthreads();  // all MFMA frag reads done; safe to reuse LDS as C
  #pragma unroll
  for (int mi = 0; mi < 4; ++mi)
    #pragma unroll
    for (int nj = 0; nj < 4; ++nj)
      #pragma unroll
      for (int r = 0; r < 4; ++r) {
        int m = wm + mi * 16 + quad * 4 + r;
        int n = wn + nj * 16 + l16;
        u.C[m * 136 + n] = f2bf(acc[mi][nj][r] + bv[nj]);
      }
  __syncthreads();

  // ---- coalesced scatter: 2048 chunks of 8 bf16 (16 B), 8 per thread
  #pragma unroll
  for (int p = 0; p < 8; ++p) {
    int c = p * 256 + t;
    int m = c >> 4, col8 = (c & 15) * 8;
    uint4 v = *(const uint4*)&u.C[m * 136 + col8];
    int mg = m0 + m;
    int b = mg >> 10, s = mg & 1023;
    int e0 = col8 & 63;
    if (MODE == 0) {
      int h = n0 >> 7;
      unsigned short* dst = (col8 >> 6) ? out1 : out0;
      *(uint4*)(dst + (((size_t)b * NH + h) * NS + s) * NE + e0) = v;
    } else {
      int h = (n0 >> 6) + (col8 >> 6);
      *(uint4*)(out0 + (((size_t)b * NH + h) * NS + s) * NE + e0) = v;
    }
  }
}

// ---------------- Flash attention, bf16 MFMA 16x16x32 (unchanged) ----------------
__global__ __launch_bounds__(256) void attn_kernel(
    const unsigned short* __restrict__ Q, const unsigned short* __restrict__ K,
    const unsigned short* __restrict__ V, float* __restrict__ out)
{
  __shared__ unsigned short Ks[2][64][72];
  __shared__ unsigned short Vst[2][64][72];
  __shared__ unsigned short Ps[64][72];

  const int t = threadIdx.x;
  const int w = t >> 6;
  const int lane = t & 63;
  const int quad = lane >> 4;
  const int l16 = lane & 15;
  const int qt = blockIdx.x, h = blockIdx.y, b = blockIdx.z;
  const size_t bh = ((size_t)b * NH + h) * NS * NE;

  const unsigned short* qrow = Q + bh + (size_t)(qt * 64 + w * 16 + l16) * NE;
  short8 aq0 = *(const short8*)(qrow + quad * 8);
  short8 aq1 = *(const short8*)(qrow + 32 + quad * 8);

  const int skey = t >> 2, sc4 = t & 3;
  const int vrp  = t >> 3, ve0 = (t & 7) * 8;

  const unsigned short* Kg = K + bh;
  const unsigned short* Vg = V + bh;

  {
    const unsigned short* kr = Kg + skey * NE + sc4 * 16;
    *(uint4*)&Ks[0][skey][sc4 * 16]     = *(const uint4*)kr;
    *(uint4*)&Ks[0][skey][sc4 * 16 + 8] = *(const uint4*)(kr + 8);
    const unsigned short* vr = Vg + (2 * vrp) * NE + ve0;
    uint4 va = *(const uint4*)vr;
    uint4 vb = *(const uint4*)(vr + NE);
    const unsigned short* pa = (const unsigned short*)&va;
    const unsigned short* pb = (const unsigned short*)&vb;
    #pragma unroll
    for (int j = 0; j < 8; ++j) {
      unsigned int wv = (unsigned int)pa[j] | ((unsigned int)pb[j] << 16);
      *(unsigned int*)&Vst[0][ve0 + j][2 * vrp] = wv;
    }
  }

  float mrow[4], lrow[4];
  floatx4 O[4];
  #pragma unroll
  for (int r = 0; r < 4; ++r) {
    mrow[r] = -INFINITY; lrow[r] = 0.f;
    O[r] = (floatx4){0.f, 0.f, 0.f, 0.f};
  }

  for (int kt = 0; kt < NS / 64; ++kt) {
    __syncthreads();
    const int bi = kt & 1;

    uint4 k0n, k1n, van, vbn;
    if (kt < 15) {
      const unsigned short* kr = Kg + (size_t)(kt + 1) * 64 * NE + skey * NE + sc4 * 16;
      k0n = *(const uint4*)kr;
      k1n = *(const uint4*)(kr + 8);
      const unsigned short* vr = Vg + (size_t)(kt + 1) * 64 * NE + (2 * vrp) * NE + ve0;
      van = *(const uint4*)vr;
      vbn = *(const uint4*)(vr + NE);
    }

    floatx4 sc[4];
    #pragma unroll
    for (int kb = 0; kb < 4; ++kb) {
      short8 b0 = *(const short8*)&Ks[bi][kb * 16 + l16][quad * 8];
      short8 b1 = *(const short8*)&Ks[bi][kb * 16 + l16][32 + quad * 8];
      floatx4 z = (floatx4){0.f, 0.f, 0.f, 0.f};
      z = __builtin_amdgcn_mfma_f32_16x16x32_bf16(aq0, b0, z, 0, 0, 0);
      sc[kb] = __builtin_amdgcn_mfma_f32_16x16x32_bf16(aq1, b1, z, 0, 0, 0);
    }

    #pragma unroll
    for (int r = 0; r < 4; ++r) {
      float tm = fmaxf(fmaxf(sc[0][r], sc[1][r]), fmaxf(sc[2][r], sc[3][r]));
      tm = fmaxf(tm, __shfl_xor(tm, 1));
      tm = fmaxf(tm, __shfl_xor(tm, 2));
      tm = fmaxf(tm, __shfl_xor(tm, 4));
      tm = fmaxf(tm, __shfl_xor(tm, 8));
      float mnew = fmaxf(mrow[r], tm);
      float alpha = __expf(mrow[r] - mnew);
      mrow[r] = mnew;
      float p0 = __expf(sc[0][r] - mnew), p1 = __expf(sc[1][r] - mnew);
      float p2 = __expf(sc[2][r] - mnew), p3 = __expf(sc[3][r] - mnew);
      float ps = p0 + p1 + p2 + p3;
      ps += __shfl_xor(ps, 1);
      ps += __shfl_xor(ps, 2);
      ps += __shfl_xor(ps, 4);
      ps += __shfl_xor(ps, 8);
      lrow[r] = lrow[r] * alpha + ps;
      O[0][r] *= alpha; O[1][r] *= alpha; O[2][r] *= alpha; O[3][r] *= alpha;
      const int prow = w * 16 + quad * 4 + r;
      Ps[prow][l16]      = f2bf(p0);
      Ps[prow][16 + l16] = f2bf(p1);
      Ps[prow][32 + l16] = f2bf(p2);
      Ps[prow][48 + l16] = f2bf(p3);
    }

    if (kt < 15) {
      const int bn = bi ^ 1;
      *(uint4*)&Ks[bn][skey][sc4 * 16]     = k0n;
      *(uint4*)&Ks[bn][skey][sc4 * 16 + 8] = k1n;
      const unsigned short* pa = (const unsigned short*)&van;
      const unsigned short* pb = (const unsigned short*)&vbn;
      #pragma unroll
      for (int j = 0; j < 8; ++j) {
        unsigned int wv = (unsigned int)pa[j] | ((unsigned int)pb[j] << 16);
        *(unsigned int*)&Vst[bn][ve0 + j][2 * vrp] = wv;
      }
    }
    __syncthreads();

    short8 pa0 = *(const short8*)&Ps[w * 16 + l16][quad * 8];
    short8 pa1 = *(const short8*)&Ps[w * 16 + l16][32 + quad * 8];
    #pragma unroll
    for (int eb = 0; eb < 4; ++eb) {
      short8 v0 = *(const short8*)&Vst[bi][eb * 16 + l16][quad * 8];
      short8 v1 = *(const short8*)&Vst[bi][eb * 16 + l16][32 + quad * 8];
      O[eb] = __builtin_amdgcn_mfma_f32_16x16x32_bf16(pa0, v0, O[eb], 0, 0, 0);
      O[eb] = __builtin_amdgcn_mfma_f32_16x16x32_bf16(pa1, v1, O[eb], 0, 0, 0);
    }
  }

  const float scaling = 0.125f;
  #pragma unroll
  for (int r = 0; r < 4; ++r) {
    float inv = scaling / lrow[r];
    int s = qt * 64 + w * 16 + quad * 4 + r;
    float* orow = out + ((size_t)b * NS + s) * (NE * NH) + h * NE;
    orow[l16]      = O[0][r] * inv;
    orow[16 + l16] = O[1][r] * inv;
    orow[32 + l16] = O[2][r] * inv;
    orow[48 + l16] = O[3][r] * inv;
  }
}

extern "C" void kernel_launch(void* const* d_in, const int* in_sizes, int n_in,
                              void* d_out, int out_size, void* d_ws, size_t ws_size,
                              hipStream_t stream) {
  const float* inputs1 = (const float*)d_in[0];
  const float* inputs2 = (const float*)d_in[1];
  const float* W_kv    = (const float*)d_in[2];
  const float* b_kv    = (const float*)d_in[3];
  const float* W_q     = (const float*)d_in[4];
  const float* b_q     = (const float*)d_in[5];
  float* out = (float*)d_out;

  const size_t plane = (size_t)NB * NH * NS * NE;  // 8,388,608
  const size_t amat  = (size_t)NB * NS * NF;       // 4,194,304
  unsigned short* Qb   = (unsigned short*)d_ws;
  unsigned short* Kb   = Qb + plane;
  unsigned short* Vb   = Kb + plane;
  unsigned short* A1b  = Vb + plane;
  unsigned short* A2b  = A1b + amat;
  unsigned short* Wtkv = A2b + amat;                // 2048*512
  unsigned short* Wtq  = Wtkv + (size_t)2048 * NF;  // 1024*512

  dim3 blk(256);
  conv_bf16<<<dim3(amat / 4 / 256), blk, 0, stream>>>(inputs1, A1b, amat / 4);
  conv_bf16<<<dim3(amat / 4 / 256), blk, 0, stream>>>(inputs2, A2b, amat / 4);
  perm_w<5><<<dim3(2048 / 64, NF / 64), blk, 0, stream>>>(W_kv, Wtkv, 2048);
  perm_w<4><<<dim3(1024 / 64, NF / 64), blk, 0, stream>>>(W_q, Wtq, 1024);
  gemm_proj<0><<<dim3(2048 / 128, 8192 / 128), blk, 0, stream>>>(
      A1b, Wtkv, b_kv, Kb, Vb);
  gemm_proj<1><<<dim3(1024 / 128, 8192 / 128), blk, 0, stream>>>(
      A2b, Wtq, b_q, Qb, nullptr);
  attn_kernel<<<dim3(NS / 64, NH, NB), blk, 0, stream>>>(Qb, Kb, Vb, out);
}

// Round 4
// 209.795 us; speedup vs baseline: 5.3234x; 1.3449x over previous
//
#include <hip/hip_runtime.h>
#include <math.h>

#define NB 8
#define NS 1024
#define NF 512
#define NE 64
#define NH 16

typedef __attribute__((ext_vector_type(8))) short short8;
typedef __attribute__((ext_vector_type(4))) float floatx4;

__device__ inline unsigned short f2bf(float f) {
  union { float f; unsigned int u; } c; c.f = f;
  unsigned int u = c.u;
  u += 0x7FFFu + ((u >> 16) & 1u);  // RNE
  return (unsigned short)(u >> 16);
}

__device__ inline void gl_lds16(const void* g, void* l) {
  __builtin_amdgcn_global_load_lds(
      (const __attribute__((address_space(1))) unsigned int*)g,
      (__attribute__((address_space(3))) unsigned int*)l, 16, 0, 0);
}

// ---------------- fp32 -> bf16 convert (row-major) -------------------------------
__global__ __launch_bounds__(256) void conv_bf16(
    const float* __restrict__ in, unsigned short* __restrict__ out, int n4)
{
  int i = blockIdx.x * 256 + threadIdx.x;
  if (i < n4) {
    float4 v = ((const float4*)in)[i];
    ushort4 o;
    o.x = f2bf(v.x); o.y = f2bf(v.y); o.z = f2bf(v.z); o.w = f2bf(v.w);
    ((ushort4*)out)[i] = o;
  }
}

// ---------------- W[k][n] fp32 -> Wt[n'][k] bf16, n' = (n&(G-1))*64 + n>>LOGG ----
template <int LOGG>
__global__ __launch_bounds__(256) void perm_w(
    const float* __restrict__ W, unsigned short* __restrict__ Wt, int N)
{
  __shared__ float T[64][65];
  const int t = threadIdx.x;
  const int k0 = blockIdx.y * 64, n0 = blockIdx.x * 64;
  #pragma unroll
  for (int p = 0; p < 4; ++p) {
    int i = (t >> 4) + p * 16, j = (t & 15) * 4;
    float4 v = *(const float4*)(W + (size_t)(k0 + i) * N + n0 + j);
    T[i][j] = v.x; T[i][j + 1] = v.y; T[i][j + 2] = v.z; T[i][j + 3] = v.w;
  }
  __syncthreads();
  #pragma unroll
  for (int p = 0; p < 2; ++p) {
    int c = p * 256 + t;
    int jn = c >> 3, kc = (c & 7) * 8;
    int n = n0 + jn;
    int g = n & ((1 << LOGG) - 1), e = n >> LOGG;
    unsigned short v[8];
    #pragma unroll
    for (int j = 0; j < 8; ++j) v[j] = f2bf(T[kc + j][jn]);
    *(uint4*)(Wt + (size_t)(g * 64 + e) * NF + k0 + kc) = *(uint4*)v;
  }
}

// ---------------- bf16 MFMA projection GEMM (m97 structure) ----------------------
// MODE 0: N=2048, cols (h,c,e); out0=K[b][h][s][e], out1=Vt[b][h][e][s] (transposed!)
// MODE 1: N=1024, cols (h,e);   out0=Q[b][h][s][e]
template <int MODE>
__global__ __launch_bounds__(256) void gemm_proj(
    const unsigned short* __restrict__ A, const unsigned short* __restrict__ Wt,
    const float* __restrict__ bias, unsigned short* __restrict__ out0,
    unsigned short* __restrict__ out1)
{
  __shared__ union {
    struct { unsigned short A[128 * 32]; unsigned short B[128 * 32]; } ab;
    unsigned short C[128 * 136];                                        // MODE 1
    struct { unsigned short K[128][72]; unsigned short V[64][136]; } kv; // MODE 0
  } u;

  const int t = threadIdx.x;
  const int w = t >> 6, l = t & 63;
  const int quad = l >> 4, l16 = l & 15;
  const int n0 = blockIdx.x * 128, m0 = blockIdx.y * 128;
  const int wm = (w >> 1) * 64, wn = (w & 1) * 64;

  floatx4 acc[4][4];
  #pragma unroll
  for (int mi = 0; mi < 4; ++mi)
    #pragma unroll
    for (int nj = 0; nj < 4; ++nj) acc[mi][nj] = (floatx4){0.f, 0.f, 0.f, 0.f};

  const int srow = l >> 2, sk = (l & 3) * 8;
  const unsigned short* Ag = A + (size_t)(m0 + w * 16 + srow) * NF + sk;
  const unsigned short* Bg = Wt + (size_t)(n0 + w * 16 + srow) * NF + sk;

  for (int k0 = 0; k0 < NF; k0 += 32) {
    __syncthreads();
    gl_lds16(Ag + k0,            &u.ab.A[(w * 16) * 32]);
    gl_lds16(Ag + 64 * NF + k0,  &u.ab.A[(64 + w * 16) * 32]);
    gl_lds16(Bg + k0,            &u.ab.B[(w * 16) * 32]);
    gl_lds16(Bg + 64 * NF + k0,  &u.ab.B[(64 + w * 16) * 32]);
    __syncthreads();

    short8 af[4], bf[4];
    #pragma unroll
    for (int mi = 0; mi < 4; ++mi)
      af[mi] = *(const short8*)&u.ab.A[(wm + mi * 16 + l16) * 32 + quad * 8];
    #pragma unroll
    for (int nj = 0; nj < 4; ++nj)
      bf[nj] = *(const short8*)&u.ab.B[(wn + nj * 16 + l16) * 32 + quad * 8];
    #pragma unroll
    for (int mi = 0; mi < 4; ++mi)
      #pragma unroll
      for (int nj = 0; nj < 4; ++nj)
        acc[mi][nj] = __builtin_amdgcn_mfma_f32_16x16x32_bf16(
            af[mi], bf[nj], acc[mi][nj], 0, 0, 0);
  }

  float bv[4];
  #pragma unroll
  for (int nj = 0; nj < 4; ++nj) {
    int np = n0 + wn + nj * 16 + l16;
    int n = (MODE == 0) ? ((np & 63) * 32 + (np >> 6)) : ((np & 63) * 16 + (np >> 6));
    bv[nj] = bias[n];
  }
  __syncthreads();  // all MFMA frag reads done; reuse LDS for C

  if (MODE == 0) {
    if (wn == 0) {
      // K half: m-major
      #pragma unroll
      for (int mi = 0; mi < 4; ++mi)
        #pragma unroll
        for (int nj = 0; nj < 4; ++nj)
          #pragma unroll
          for (int r = 0; r < 4; ++r)
            u.kv.K[wm + mi * 16 + quad * 4 + r][nj * 16 + l16] =
                f2bf(acc[mi][nj][r] + bv[nj]);
    } else {
      // V half: e-major (transposed) so scatter writes s-contiguous chunks
      #pragma unroll
      for (int mi = 0; mi < 4; ++mi)
        #pragma unroll
        for (int nj = 0; nj < 4; ++nj)
          #pragma unroll
          for (int r = 0; r < 4; ++r)
            u.kv.V[nj * 16 + l16][wm + mi * 16 + quad * 4 + r] =
                f2bf(acc[mi][nj][r] + bv[nj]);
    }
  } else {
    #pragma unroll
    for (int mi = 0; mi < 4; ++mi)
      #pragma unroll
      for (int nj = 0; nj < 4; ++nj)
        #pragma unroll
        for (int r = 0; r < 4; ++r)
          u.C[(wm + mi * 16 + quad * 4 + r) * 136 + wn + nj * 16 + l16] =
              f2bf(acc[mi][nj][r] + bv[nj]);
  }
  __syncthreads();

  if (MODE == 0) {
    const int h = n0 >> 7, btile = m0 >> 10, s0 = m0 & 1023;
    #pragma unroll
    for (int p = 0; p < 4; ++p) {  // K: 1024 chunks
      int c = p * 256 + t;
      int m = c >> 3, ec = c & 7;
      uint4 v = *(const uint4*)&u.kv.K[m][ec * 8];
      *(uint4*)(out0 + (((size_t)btile * NH + h) * NS + s0 + m) * NE + ec * 8) = v;
    }
    #pragma unroll
    for (int p = 0; p < 4; ++p) {  // V: 1024 chunks into Vt[b][h][e][s]
      int c = p * 256 + t;
      int e = c >> 4, mc = c & 15;
      uint4 v = *(const uint4*)&u.kv.V[e][mc * 8];
      *(uint4*)(out1 + (((size_t)btile * NH + h) * NE + e) * NS + s0 + mc * 8) = v;
    }
  } else {
    #pragma unroll
    for (int p = 0; p < 8; ++p) {
      int c = p * 256 + t;
      int m = c >> 4, col8 = (c & 15) * 8;
      uint4 v = *(const uint4*)&u.C[m * 136 + col8];
      int mg = m0 + m, b = mg >> 10, s = mg & 1023;
      int h = (n0 >> 6) + (col8 >> 6), e0 = col8 & 63;
      *(uint4*)(out0 + (((size_t)b * NH + h) * NS + s) * NE + e0) = v;
    }
  }
}

// ---------------- Flash attention, bf16 MFMA, 128-row Q tiles --------------------
// grid (S/128, H, B), 256 thr = 4 waves; wave w: rows w*32 + rb*16 + l16, rb=0,1.
// No max-tracking (logits bounded ~10); 1 barrier/tile; XOR-swizzled K/V staging.
__global__ __launch_bounds__(256) void attn_kernel(
    const unsigned short* __restrict__ Q, const unsigned short* __restrict__ K,
    const unsigned short* __restrict__ Vt, float* __restrict__ out)
{
  __shared__ unsigned short Ks[2][64][64];  // [buf][key][e], chunk^=(key&7)
  __shared__ unsigned short Vs[2][64][64];  // [buf][e][key], chunk^=(e&7)
  __shared__ unsigned short Ps[128][72];    // [q][key], wave-private rows

  const int t = threadIdx.x;
  const int w = t >> 6, lane = t & 63;
  const int quad = lane >> 4, l16 = lane & 15;
  const int qt = blockIdx.x, h = blockIdx.y, b = blockIdx.z;
  const size_t bh = ((size_t)b * NH + h) * NS * NE;

  short8 aq[2][2];
  #pragma unroll
  for (int rb = 0; rb < 2; ++rb) {
    const unsigned short* qrow =
        Q + bh + (size_t)(qt * 128 + w * 32 + rb * 16 + l16) * NE;
    aq[rb][0] = *(const short8*)(qrow + quad * 8);
    aq[rb][1] = *(const short8*)(qrow + 32 + quad * 8);
  }

  const int sr = t >> 3, sc8 = t & 7;          // staging: rows sr, sr+32
  const int xs = (sc8 ^ (sr & 7)) * 8;         // swizzled store offset
  const int xq = (quad ^ (l16 & 7)) * 8;       // swizzled frag-read offset
  const unsigned short* Kg = K + bh;           // [key][e]
  const unsigned short* Vg = Vt + bh;          // [e][s]

  {
    *(uint4*)&Ks[0][sr][xs]      = *(const uint4*)(Kg + (size_t)sr * NE + sc8 * 8);
    *(uint4*)&Ks[0][32 + sr][xs] = *(const uint4*)(Kg + (size_t)(32 + sr) * NE + sc8 * 8);
    *(uint4*)&Vs[0][sr][xs]      = *(const uint4*)(Vg + (size_t)sr * NS + sc8 * 8);
    *(uint4*)&Vs[0][32 + sr][xs] = *(const uint4*)(Vg + (size_t)(32 + sr) * NS + sc8 * 8);
  }

  float lrow[2][4];
  floatx4 O[2][4];
  #pragma unroll
  for (int rb = 0; rb < 2; ++rb)
    #pragma unroll
    for (int j = 0; j < 4; ++j) {
      lrow[rb][j] = 0.f;
      O[rb][j] = (floatx4){0.f, 0.f, 0.f, 0.f};
    }

  for (int kt = 0; kt < NS / 64; ++kt) {
    __syncthreads();  // buf[bi] staged; prev PV reads of buf[bi^1]/Ps done
    const int bi = kt & 1;

    uint4 kn0, kn1, vn0, vn1;
    if (kt < 15) {
      const unsigned short* kg = Kg + (size_t)(kt + 1) * 64 * NE;
      kn0 = *(const uint4*)(kg + (size_t)sr * NE + sc8 * 8);
      kn1 = *(const uint4*)(kg + (size_t)(32 + sr) * NE + sc8 * 8);
      const unsigned short* vg = Vg + (kt + 1) * 64;
      vn0 = *(const uint4*)(vg + (size_t)sr * NS + sc8 * 8);
      vn1 = *(const uint4*)(vg + (size_t)(32 + sr) * NS + sc8 * 8);
    }

    // K frags once, shared by both row-blocks
    short8 kf0[4], kf1[4];
    #pragma unroll
    for (int kb = 0; kb < 4; ++kb) {
      kf0[kb] = *(const short8*)&Ks[bi][kb * 16 + l16][xq];
      kf1[kb] = *(const short8*)&Ks[bi][kb * 16 + l16][xq ^ 32];
    }

    #pragma unroll
    for (int rb = 0; rb < 2; ++rb) {
      floatx4 sc[4];
      #pragma unroll
      for (int kb = 0; kb < 4; ++kb) {
        floatx4 z = (floatx4){0.f, 0.f, 0.f, 0.f};
        z = __builtin_amdgcn_mfma_f32_16x16x32_bf16(aq[rb][0], kf0[kb], z, 0, 0, 0);
        sc[kb] = __builtin_amdgcn_mfma_f32_16x16x32_bf16(aq[rb][1], kf1[kb], z, 0, 0, 0);
      }
      #pragma unroll
      for (int r = 0; r < 4; ++r) {
        float p0 = __expf(sc[0][r]), p1 = __expf(sc[1][r]);
        float p2 = __expf(sc[2][r]), p3 = __expf(sc[3][r]);
        lrow[rb][r] += (p0 + p1) + (p2 + p3);
        const int prow = w * 32 + rb * 16 + quad * 4 + r;
        Ps[prow][l16]      = f2bf(p0);
        Ps[prow][16 + l16] = f2bf(p1);
        Ps[prow][32 + l16] = f2bf(p2);
        Ps[prow][48 + l16] = f2bf(p3);
      }
    }

    if (kt < 15) {  // stage next tile into other buffer
      const int bn = bi ^ 1;
      *(uint4*)&Ks[bn][sr][xs]      = kn0;
      *(uint4*)&Ks[bn][32 + sr][xs] = kn1;
      *(uint4*)&Vs[bn][sr][xs]      = vn0;
      *(uint4*)&Vs[bn][32 + sr][xs] = vn1;
    }

    // PV (Ps rows are wave-private: lgkmcnt ordering suffices, no barrier)
    short8 vf0[4], vf1[4];
    #pragma unroll
    for (int eb = 0; eb < 4; ++eb) {
      vf0[eb] = *(const short8*)&Vs[bi][eb * 16 + l16][xq];
      vf1[eb] = *(const short8*)&Vs[bi][eb * 16 + l16][xq ^ 32];
    }
    #pragma unroll
    for (int rb = 0; rb < 2; ++rb) {
      short8 pa0 = *(const short8*)&Ps[w * 32 + rb * 16 + l16][quad * 8];
      short8 pa1 = *(const short8*)&Ps[w * 32 + rb * 16 + l16][32 + quad * 8];
      #pragma unroll
      for (int eb = 0; eb < 4; ++eb) {
        O[rb][eb] = __builtin_amdgcn_mfma_f32_16x16x32_bf16(pa0, vf0[eb], O[rb][eb], 0, 0, 0);
        O[rb][eb] = __builtin_amdgcn_mfma_f32_16x16x32_bf16(pa1, vf1[eb], O[rb][eb], 0, 0, 0);
      }
    }
  }

  const float scaling = 0.125f;  // softmax THEN * 1/sqrt(E)
  #pragma unroll
  for (int rb = 0; rb < 2; ++rb)
    #pragma unroll
    for (int r = 0; r < 4; ++r) {
      float lv = lrow[rb][r];
      lv += __shfl_xor(lv, 1); lv += __shfl_xor(lv, 2);
      lv += __shfl_xor(lv, 4); lv += __shfl_xor(lv, 8);
      float inv = scaling / lv;
      int s = qt * 128 + w * 32 + rb * 16 + quad * 4 + r;
      float* orow = out + ((size_t)b * NS + s) * (NE * NH) + h * NE;
      orow[l16]      = O[rb][0][r] * inv;
      orow[16 + l16] = O[rb][1][r] * inv;
      orow[32 + l16] = O[rb][2][r] * inv;
      orow[48 + l16] = O[rb][3][r] * inv;
    }
}

extern "C" void kernel_launch(void* const* d_in, const int* in_sizes, int n_in,
                              void* d_out, int out_size, void* d_ws, size_t ws_size,
                              hipStream_t stream) {
  const float* inputs1 = (const float*)d_in[0];
  const float* inputs2 = (const float*)d_in[1];
  const float* W_kv    = (const float*)d_in[2];
  const float* b_kv    = (const float*)d_in[3];
  const float* W_q     = (const float*)d_in[4];
  const float* b_q     = (const float*)d_in[5];
  float* out = (float*)d_out;

  const size_t plane = (size_t)NB * NH * NS * NE;  // 8,388,608
  const size_t amat  = (size_t)NB * NS * NF;       // 4,194,304
  unsigned short* Qb   = (unsigned short*)d_ws;
  unsigned short* Kb   = Qb + plane;
  unsigned short* Vtb  = Kb + plane;
  unsigned short* A1b  = Vtb + plane;
  unsigned short* A2b  = A1b + amat;
  unsigned short* Wtkv = A2b + amat;
  unsigned short* Wtq  = Wtkv + (size_t)2048 * NF;

  dim3 blk(256);
  conv_bf16<<<dim3(amat / 4 / 256), blk, 0, stream>>>(inputs1, A1b, amat / 4);
  conv_bf16<<<dim3(amat / 4 / 256), blk, 0, stream>>>(inputs2, A2b, amat / 4);
  perm_w<5><<<dim3(2048 / 64, NF / 64), blk, 0, stream>>>(W_kv, Wtkv, 2048);
  perm_w<4><<<dim3(1024 / 64, NF / 64), blk, 0, stream>>>(W_q, Wtq, 1024);
  gemm_proj<0><<<dim3(2048 / 128, 8192 / 128), blk, 0, stream>>>(
      A1b, Wtkv, b_kv, Kb, Vtb);
  gemm_proj<1><<<dim3(1024 / 128, 8192 / 128), blk, 0, stream>>>(
      A2b, Wtq, b_q, Qb, nullptr);
  attn_kernel<<<dim3(NS / 128, NH, NB), blk, 0, stream>>>(Qb, Kb, Vtb, out);
}